// Round 10
// baseline (113.740 us; speedup 1.0000x reference)
//
#include <hip/hip_runtime.h>
#include <hip/hip_bf16.h>
#include <stdint.h>

typedef __bf16 bf16;
typedef __bf16 bf16x8 __attribute__((ext_vector_type(8)));
typedef __bf16 bf16x4 __attribute__((ext_vector_type(4)));
typedef float f32x4 __attribute__((ext_vector_type(4)));

#define KDIM 768
#define NHEAD 12
#define HDIM 64
#define NTOK 1024
#define BATCH 8
#define QKVW 2304

// XOR swizzle for row-major [row][128B-row] LDS tiles (attention)
#define SWZ(row, b) ((b) ^ (((row) & 7) << 4))

__device__ __forceinline__ void gl_lds16(const bf16* g, bf16* l) {
    __builtin_amdgcn_global_load_lds((const __attribute__((address_space(1))) void*)g,
                                     (__attribute__((address_space(3))) void*)l, 16, 0, 0);
}

#define G_MFMA(a, b, c) __builtin_amdgcn_mfma_f32_16x16x32_bf16(a, b, c, 0, 0, 0)
#define VMW(N) asm volatile("s_waitcnt vmcnt(" #N ")" ::: "memory")

// ---------------- fp32 -> bf16 convert (weights only; x is fused into qkv) ----------
__global__ void k_cvt_w(const float* __restrict__ wq, const float* __restrict__ wp,
                        bf16* __restrict__ wqb, bf16* __restrict__ wpb) {
    int b = blockIdx.x;
    const float* src;
    bf16* dst;
    int base;
    if (b < 1728) { src = wq; dst = wqb; base = b; }
    else          { src = wp; dst = wpb; base = b - 1728; }
    int i = (base * 256 + threadIdx.x) * 4;
    float4 v = *(const float4*)(src + i);
    bf16x4 o;
    o[0] = (bf16)v.x; o[1] = (bf16)v.y; o[2] = (bf16)v.z; o[3] = (bf16)v.w;
    *(bf16x4*)(dst + i) = o;
}

// =====================================================================================
// QKV GEMM, cvt-fused: 128(M) x 192(N) x K, BK=32, 4 waves (2x2), per-wave 64x96.
// A (x, fp32): reg-staged (T14) — float4 loads for tile kt+2 issued at top of kt into
// static sets rE/rO; retired by the end-of-tile counted vmcnt(4); converted and
// ds_write'd (swizzled) to a 3-slot A ring. B (w_qkv bf16): gl_lds, pre-swizzled
// source, 2-slot ring, issued 1 tile ahead (L2-resident W). One barrier per K-tile.
// Slot algebra (verified): tile kt reads sA[kt%3], sB[kt&1]; issues B(kt+1)->sB[~],
// A(kt+2)->reg; end-of-tile writes A(kt+1)->sA[(kt+1)%3] (last read at kt-2).
// vmcnt(4) drains exactly {A(kt+1) 4 loads, B(kt+1) 3 gl_lds} (issue order B-then-A
// inverted: B first so it's older). Output: row-major [8192][2304] bf16 (coalesced),
// q-scaled; attention reads strided views.
// =====================================================================================

#define AISS(R, kt) do {                                                        \
    const float* p_ = Xst + (size_t)(kt) * 32;                                  \
    R[0] = *(const float4*)(p_);                                                \
    R[1] = *(const float4*)(p_ + 4);                                            \
    R[2] = *(const float4*)(p_ + (size_t)64 * KDIM);                            \
    R[3] = *(const float4*)(p_ + (size_t)64 * KDIM + 4);                        \
} while (0)

#define BISS(slot, kt) do {                                                     \
    const bf16* p_ = Wst + (size_t)(kt) * 32;                                   \
    gl_lds16(p_,                       &sB[slot][t * 8]);                       \
    gl_lds16(p_ + (size_t)64 * KDIM,   &sB[slot][t * 8 + 2048]);                \
    gl_lds16(p_ + (size_t)128 * KDIM,  &sB[slot][t * 8 + 4096]);                \
} while (0)

#define AWRT(R, slot) do {                                                      \
    bf16x8 v0, v1;                                                              \
    v0[0] = (bf16)R[0].x; v0[1] = (bf16)R[0].y; v0[2] = (bf16)R[0].z; v0[3] = (bf16)R[0].w; \
    v0[4] = (bf16)R[1].x; v0[5] = (bf16)R[1].y; v0[6] = (bf16)R[1].z; v0[7] = (bf16)R[1].w; \
    v1[0] = (bf16)R[2].x; v1[1] = (bf16)R[2].y; v1[2] = (bf16)R[2].z; v1[3] = (bf16)R[2].w; \
    v1[4] = (bf16)R[3].x; v1[5] = (bf16)R[3].y; v1[6] = (bf16)R[3].z; v1[7] = (bf16)R[3].w; \
    char* dp_ = (char*)&sA[0][0] + (slot) * 8192 + srow * 64 + swb;             \
    *(bf16x8*)dp_ = v0;                                                         \
    *(bf16x8*)(dp_ + 4096) = v1;                                                \
} while (0)

#define QTILE(ASL, BSL, RISS, RWRT, I_) do {                                    \
    const int kt = g6 + (I_);                                                   \
    const char* A8 = (const char*)sA[ASL];                                      \
    const char* B8 = (const char*)sB[BSL];                                      \
    bf16x8 af0 = *(const bf16x8*)(A8 + (wr * 64 +  0 + lr) * 64 + kxoff);       \
    bf16x8 af1 = *(const bf16x8*)(A8 + (wr * 64 + 16 + lr) * 64 + kxoff);       \
    bf16x8 af2 = *(const bf16x8*)(A8 + (wr * 64 + 32 + lr) * 64 + kxoff);       \
    bf16x8 af3 = *(const bf16x8*)(A8 + (wr * 64 + 48 + lr) * 64 + kxoff);       \
    bf16x8 bfr[6];                                                              \
    _Pragma("unroll")                                                           \
    for (int n = 0; n < 6; ++n)                                                 \
        bfr[n] = *(const bf16x8*)(B8 + (wc * 96 + n * 16 + lr) * 64 + kxoff);   \
    if (kt + 1 < 24) BISS((BSL) ^ 1, kt + 1);                                   \
    if (kt + 2 < 24) AISS(RISS, kt + 2);                                        \
    __builtin_amdgcn_s_setprio(1);                                              \
    _Pragma("unroll")                                                           \
    for (int n = 0; n < 6; ++n) {                                               \
        acc[0][n] = G_MFMA(af0, bfr[n], acc[0][n]);                             \
        acc[1][n] = G_MFMA(af1, bfr[n], acc[1][n]);                             \
    }                                                                           \
    __builtin_amdgcn_s_setprio(0);                                              \
    __builtin_amdgcn_s_setprio(1);                                              \
    _Pragma("unroll")                                                           \
    for (int n = 0; n < 6; ++n) {                                               \
        acc[2][n] = G_MFMA(af2, bfr[n], acc[2][n]);                             \
        acc[3][n] = G_MFMA(af3, bfr[n], acc[3][n]);                             \
    }                                                                           \
    __builtin_amdgcn_s_setprio(0);                                              \
    if (kt < 22)       { VMW(4); }                                              \
    else if (kt == 22) { VMW(0); }                                              \
    if (kt < 23) {                                                              \
        AWRT(RWRT, ((ASL) + 1) % 3);                                            \
        asm volatile("s_waitcnt lgkmcnt(0)" ::: "memory");                      \
        __builtin_amdgcn_s_barrier();                                           \
    }                                                                           \
} while (0)

__global__ __launch_bounds__(256, 2) void k_gemm_qkv(
    const float* __restrict__ X, const bf16* __restrict__ W,
    bf16* __restrict__ qkvb)
{
    __shared__ __attribute__((aligned(16))) bf16 sA[3][4096];   // 128 rows x 32, x3
    __shared__ __attribute__((aligned(16))) bf16 sB[2][6144];   // 192 rows x 32, x2
    const int t = threadIdx.x;
    const int lane = t & 63;
    const int wv = t >> 6;
    const int wr = wv >> 1, wc = wv & 1;
    const int lr = lane & 15, lg = lane >> 4;
    const int kxoff = (lg << 4) ^ (((lr >> 1) & 3) << 4);
    const int srow = t >> 2;
    const int swb = (((t & 3) ^ ((t >> 3) & 3))) << 4;           // swizzled LDS byte pos
    const int spos = (((t & 3) ^ ((t >> 3) & 3))) * 8;           // pre-swizzled B source
    const int bm = blockIdx.x, bn = blockIdx.y;
    const float* Xst = X + (size_t)(bm * 128 + srow) * KDIM + (t & 3) * 8;  // linear src
    const bf16* Wst  = W + (size_t)(bn * 192 + srow) * KDIM + spos;
    f32x4 acc[4][6] = {};
    float4 rE[4], rO[4];

    // prologue: A(0)->rE, B(0)->sB[0]; drain A0; write sA[0]; A(1)->rE; drain B0
    AISS(rE, 0);
    BISS(0, 0);
    VMW(3);
    AWRT(rE, 0);
    AISS(rE, 1);
    VMW(4);
    asm volatile("s_waitcnt lgkmcnt(0)" ::: "memory");
    __builtin_amdgcn_s_barrier();

#pragma unroll 1
    for (int g = 0; g < 4; ++g) {
        const int g6 = g * 6;
        QTILE(0, 0, rO, rE, 0);
        QTILE(1, 1, rE, rO, 1);
        QTILE(2, 0, rO, rE, 2);
        QTILE(0, 1, rE, rO, 3);
        QTILE(1, 0, rO, rE, 4);
        QTILE(2, 1, rE, rO, 5);
    }

    // epilogue: row-major [8192][2304], q-scaled (coalesced 32B segments per 16 lanes)
    const float QSC = 0.18033688011112042f;  // 0.125 * log2(e) folded into q
#pragma unroll
    for (int n = 0; n < 6; ++n) {
        int o = bn * 192 + wc * 96 + n * 16 + lr;
        float sc = (o < 768) ? QSC : 1.0f;
#pragma unroll
        for (int m = 0; m < 4; ++m) {
            int row = bm * 128 + wr * 64 + m * 16 + lg * 4;
#pragma unroll
            for (int r = 0; r < 4; ++r)
                qkvb[(size_t)(row + r) * QKVW + o] = (bf16)(acc[m][n][r] * sc);
        }
    }
}

// =====================================================================================
// Proj GEMM: r9-exact (128x128x32, depth-2 counted vmcnt, swizzled, 32KB)
// =====================================================================================
#define P_STAGE(Ab, Wb, Abuf, Bbuf, k0) do {                                    \
    gl_lds16((Ab) + (size_t)sr0 * KDIM + (k0) + sc0, (Abuf) + wv * 512);        \
    gl_lds16((Ab) + (size_t)sr1 * KDIM + (k0) + sc1, (Abuf) + 2048 + wv * 512); \
    gl_lds16((Wb) + (size_t)sr0 * KDIM + (k0) + sc0, (Bbuf) + wv * 512);        \
    gl_lds16((Wb) + (size_t)sr1 * KDIM + (k0) + sc1, (Bbuf) + 2048 + wv * 512); \
} while (0)

__global__ __launch_bounds__(256) void k_gemm_proj(
    const bf16* __restrict__ A, const bf16* __restrict__ W,
    const float* __restrict__ bias, float* __restrict__ out)
{
    __shared__ bf16 As[2][4096];
    __shared__ bf16 Bs[2][4096];
    const int t = threadIdx.x;
    const int lane = t & 63;
    const int wv = t >> 6;
    const int wr = wv >> 1, wc = wv & 1;
    const int lr = lane & 15, lg = lane >> 4;
    const int q0 = wv * 64 + lane;
    const int R0 = q0 >> 3, wp0 = (q0 & 7) ^ (R0 & 7);
    const int sr0 = 2 * R0 + (wp0 >> 2), sc0 = (wp0 & 3) * 8;
    const int q1 = 256 + wv * 64 + lane;
    const int R1 = q1 >> 3, wp1 = (q1 & 7) ^ (R1 & 7);
    const int sr1 = 2 * R1 + (wp1 >> 2), sc1 = (wp1 & 3) * 8;
    const int rhalf = lr >> 1;
    const int xorp = (((lr & 1) * 64 + lg * 16) ^ (rhalf << 4));
    const int bm = blockIdx.x, bn = blockIdx.y;
    const bf16* Ab = A + (size_t)bm * 128 * KDIM;
    const bf16* Wb = W + (size_t)bn * 128 * KDIM;

    f32x4 acc[4][4] = {};
    P_STAGE(Ab, Wb, As[0], Bs[0], 0);
    P_STAGE(Ab, Wb, As[1], Bs[1], 32);
    VMW(4);
    __builtin_amdgcn_s_barrier();
#pragma unroll 1
    for (int tt = 0; tt < 24; ++tt) {
        int p = tt & 1;
        const char* Ab8 = (const char*)As[p];
        const char* Bb8 = (const char*)Bs[p];
        bf16x8 af[4], bfr[4];
#pragma unroll
        for (int m = 0; m < 4; ++m)
            af[m] = *(const bf16x8*)(Ab8 + (wr * 32 + m * 8 + rhalf) * 128 + xorp);
#pragma unroll
        for (int n = 0; n < 4; ++n)
            bfr[n] = *(const bf16x8*)(Bb8 + (wc * 32 + n * 8 + rhalf) * 128 + xorp);
        asm volatile("s_waitcnt lgkmcnt(0)" ::: "memory");
        __builtin_amdgcn_s_barrier();
        if (tt < 22) {
            P_STAGE(Ab, Wb, As[p], Bs[p], (tt + 2) * 32);
            __builtin_amdgcn_sched_barrier(0);
        }
#pragma unroll
        for (int m = 0; m < 4; ++m)
#pragma unroll
            for (int n = 0; n < 4; ++n)
                acc[m][n] = G_MFMA(af[m], bfr[n], acc[m][n]);
        if (tt < 22)       { VMW(4); }
        else if (tt == 22) { VMW(0); }
        __builtin_amdgcn_s_barrier();
    }

#pragma unroll
    for (int n = 0; n < 4; ++n) {
        int col = bn * 128 + wc * 64 + n * 16 + lr;
        float bv = bias[col];
#pragma unroll
        for (int m = 0; m < 4; ++m) {
            int grow = bm * 128 + wr * 64 + m * 16 + lg * 4;
#pragma unroll
            for (int r = 0; r < 4; ++r)
                out[(size_t)(grow + r) * KDIM + col] = acc[m][n][r] + bv;
        }
    }
}

// ---------------- banded flash attention (reads strided q/k/v views of qkvb) --------
__global__ __launch_bounds__(256) void k_attn(
    const bf16* __restrict__ qkvb, bf16* __restrict__ ob)
{
    const int x = blockIdx.x;
    const int sub = x >> 3;
    const int bh = (x & 7) * 12 + (sub >> 4);   // 12 bh per XCD
    const int qblk = sub & 15;                   // == h_q
    const int head = bh % NHEAD, bidx = bh / NHEAD;
    // strided views: row r, col c -> BH[(size_t)r*2304 + part + c]
    const bf16* BH = qkvb + (size_t)bidx * NTOK * QKVW + head * 64;

    const int t = threadIdx.x, lane = t & 63, wv = t >> 6;
    const int lr = lane & 15, lg = lane >> 4, lkb = lg * 8;

    __shared__ bf16 Ks[2][64 * 64];   // [key][d], swizzled
    __shared__ bf16 vT[2][64 * 64];   // [d][key], swizzled
    __shared__ bf16 pls[4][16 * 64];  // per-wave P [q][key], swizzled

    {
        bf16x8 z = {};
        *(bf16x8*)&pls[wv][lane * 16] = z;
        *(bf16x8*)&pls[wv][lane * 16 + 8] = z;
    }

    bf16x8 qf[2];
#pragma unroll
    for (int ks = 0; ks < 2; ++ks)
        qf[ks] = *(const bf16x8*)(BH + (size_t)(qblk * 64 + wv * 16 + lr) * QKVW + ks * 32 + lkb);

    f32x4 acc[4] = {};
    float mrow[4] = {-1e30f, -1e30f, -1e30f, -1e30f};
    float lrow[4] = {0.f, 0.f, 0.f, 0.f};

    const int kh0 = (qblk - 3 < 0) ? 0 : qblk - 3;
    const int kh1 = (qblk + 3 > 15) ? 15 : qblk + 3;

    const int sj = t >> 2;
    const int sd = (t & 3) * 16;

    const bf16* ks0 = BH + 768 + (size_t)(kh0 * 64 + sj) * QKVW + sd;
    const bf16* vs0 = BH + 1536 + (size_t)(kh0 * 64 + sj) * QKVW + sd;
    bf16x8 gk0 = *(const bf16x8*)ks0, gk1 = *(const bf16x8*)(ks0 + 8);
    bf16x8 gv0 = *(const bf16x8*)vs0, gv1 = *(const bf16x8*)(vs0 + 8);

    char* pb8 = (char*)pls[wv];
    const int wq0 = wv * 16 + lg * 4;
    int cur = 0;

    for (int kh = kh0; kh <= kh1; ++kh) {
        char* kb8 = (char*)Ks[cur];
        char* vb8 = (char*)vT[cur];
        {
            int kbo = sj * 128 + sd * 2;
            *(bf16x8*)(kb8 + SWZ(sj, kbo)) = gk0;
            *(bf16x8*)(kb8 + SWZ(sj, kbo + 16)) = gk1;
        }
#pragma unroll
        for (int ii = 0; ii < 8; ++ii) {
            int d = sd + ii;
            *(bf16*)(vb8 + SWZ(d, (d << 7) + (sj << 1))) = gv0[ii];
        }
#pragma unroll
        for (int ii = 0; ii < 8; ++ii) {
            int d = sd + 8 + ii;
            *(bf16*)(vb8 + SWZ(d, (d << 7) + (sj << 1))) = gv1[ii];
        }
        if (kh < kh1) {
            const bf16* kn = BH + 768 + (size_t)((kh + 1) * 64 + sj) * QKVW + sd;
            const bf16* vn = BH + 1536 + (size_t)((kh + 1) * 64 + sj) * QKVW + sd;
            gk0 = *(const bf16x8*)kn; gk1 = *(const bf16x8*)(kn + 8);
            gv0 = *(const bf16x8*)vn; gv1 = *(const bf16x8*)(vn + 8);
        }
        asm volatile("s_waitcnt lgkmcnt(0)" ::: "memory");
        __builtin_amdgcn_s_barrier();

        f32x4 s[3];
#pragma unroll
        for (int jj = 0; jj < 3; ++jj) {
            int j = wv - 1 + jj;
            if (j >= 0 && j <= 3) {
                int key = j * 16 + lr;
                int kbase = key * 128;
                bf16x8 kf0 = *(const bf16x8*)(kb8 + SWZ(key, kbase + lg * 16));
                bf16x8 kf1 = *(const bf16x8*)(kb8 + SWZ(key, kbase + 64 + lg * 16));
                f32x4 sv = {};
                sv = __builtin_amdgcn_mfma_f32_16x16x32_bf16(qf[0], kf0, sv, 0, 0, 0);
                sv = __builtin_amdgcn_mfma_f32_16x16x32_bf16(qf[1], kf1, sv, 0, 0, 0);
#pragma unroll
                for (int r = 0; r < 4; ++r) {
                    int dw = wq0 + r - key;
                    sv[r] = (dw >= -5 && dw <= 5) ? sv[r] : -1e30f;
                }
                s[jj] = sv;
            } else {
                s[jj] = f32x4{-1e30f, -1e30f, -1e30f, -1e30f};
            }
        }

        float pm[4], scl[4];
#pragma unroll
        for (int r = 0; r < 4; ++r) pm[r] = fmaxf(fmaxf(s[0][r], s[1][r]), s[2][r]);
#pragma unroll
        for (int off = 1; off < 16; off <<= 1)
#pragma unroll
            for (int r = 0; r < 4; ++r) pm[r] = fmaxf(pm[r], __shfl_xor(pm[r], off));
#pragma unroll
        for (int r = 0; r < 4; ++r) {
            float mn = fmaxf(mrow[r], pm[r]);
            scl[r] = exp2f(mrow[r] - mn);
            mrow[r] = mn;
        }
#pragma unroll
        for (int dt = 0; dt < 4; ++dt)
#pragma unroll
            for (int r = 0; r < 4; ++r) acc[dt][r] *= scl[r];

        float psum[4] = {0.f, 0.f, 0.f, 0.f};
#pragma unroll
        for (int jj = 0; jj < 3; ++jj) {
            int j = wv - 1 + jj;
            if (j >= 0 && j <= 3) {
#pragma unroll
                for (int r = 0; r < 4; ++r) {
                    float p = exp2f(s[jj][r] - mrow[r]);
                    psum[r] += p;
                    int row = lg * 4 + r;
                    *(bf16*)(pb8 + SWZ(row, row * 128 + (j * 16 + lr) * 2)) = (bf16)p;
                }
            }
        }
#pragma unroll
        for (int r = 0; r < 4; ++r) lrow[r] = lrow[r] * scl[r] + psum[r];

        bf16x8 pf0 = *(const bf16x8*)(pb8 + SWZ(lr, lr * 128 + lg * 16));
        bf16x8 pf1 = *(const bf16x8*)(pb8 + SWZ(lr, lr * 128 + 64 + lg * 16));
#pragma unroll
        for (int dt = 0; dt < 4; ++dt) {
            int vrow = dt * 16 + lr;
            bf16x8 vf0 = *(const bf16x8*)(vb8 + SWZ(vrow, vrow * 128 + lg * 16));
            bf16x8 vf1 = *(const bf16x8*)(vb8 + SWZ(vrow, vrow * 128 + 64 + lg * 16));
            acc[dt] = __builtin_amdgcn_mfma_f32_16x16x32_bf16(pf0, vf0, acc[dt], 0, 0, 0);
            acc[dt] = __builtin_amdgcn_mfma_f32_16x16x32_bf16(pf1, vf1, acc[dt], 0, 0, 0);
        }
        cur ^= 1;
    } // kh

#pragma unroll
    for (int off = 1; off < 16; off <<= 1)
#pragma unroll
        for (int r = 0; r < 4; ++r) lrow[r] += __shfl_xor(lrow[r], off);

#pragma unroll
    for (int r = 0; r < 4; ++r) {
        float inv = 1.0f / lrow[r];
        int tok = qblk * 64 + wv * 16 + lg * 4 + r;
        size_t rowbase = ((size_t)bidx * NTOK + tok) * KDIM + head * HDIM;
#pragma unroll
        for (int dt = 0; dt < 4; ++dt)
            ob[rowbase + dt * 16 + lr] = (bf16)(acc[dt][r] * inv);
    }
}

// ---------------- launcher ----------------
extern "C" void kernel_launch(void* const* d_in, const int* in_sizes, int n_in,
                              void* d_out, int out_size, void* d_ws, size_t ws_size,
                              hipStream_t stream) {
    const float* x      = (const float*)d_in[0];
    const float* w_qkv  = (const float*)d_in[1];
    const float* w_proj = (const float*)d_in[2];
    const float* b_proj = (const float*)d_in[3];
    float* out = (float*)d_out;

    char* ws = (char*)d_ws;
    bf16* qkvb = (bf16*)(ws);                 // 8192*2304*2 = 37748736
    bf16* wqb  = (bf16*)(ws + 37748736);      // 2304*768*2  =  3538944
    bf16* wpb  = (bf16*)(ws + 41287680);      // 768*768*2   =  1179648
    bf16* aob  = (bf16*)(ws + 42467328);      // 8192*768*2  = 12582912

    hipLaunchKernelGGL(k_cvt_w,    dim3(2304), dim3(256), 0, stream, w_qkv, w_proj, wqb, wpb);
    hipLaunchKernelGGL(k_gemm_qkv, dim3(64, 12), dim3(256), 0, stream, x, wqb, qkvb);
    hipLaunchKernelGGL(k_attn,     dim3(1536), dim3(256), 0, stream, qkvb, aob);
    hipLaunchKernelGGL(k_gemm_proj, dim3(64, 6), dim3(256), 0, stream, aob, wpb, b_proj, out);
}